// Round 8
// baseline (1081.572 us; speedup 1.0000x reference)
//
#include <hip/hip_runtime.h>

#define N_NODES 10000
#define N_EDGES 320000
#define OBS_DIM 30
#define ACT_DIM 4
#define HID 128
#define ELL_W 96   // padded neighbor-list width; deg ~Poisson(32), P(deg>88) ~ 1e-12
#define SENT N_NODES
#define GRID 512   // co-resident: LDS 48.6KB -> 3 blk/CU; 512 <= 3*256
#define TPB 512

// ---------------- init: cnt=0, bar=0, xpad rows (obs|act|0)+zero sentinel, y2 sentinel=0

__global__ __launch_bounds__(256) void k_init(int* __restrict__ cnt,
                                              unsigned* __restrict__ bar,
                                              float* __restrict__ xpad,
                                              float* __restrict__ y2,
                                              const float* __restrict__ obs,
                                              const float* __restrict__ act) {
    int i = blockIdx.x * 256 + threadIdx.x;
    if (i < (N_NODES + 1) * 16) {
        int row = i >> 4, sub = i & 15;
        float4 v = make_float4(0.f, 0.f, 0.f, 0.f);
        if (row < N_NODES) {
            float* vv = &v.x;
#pragma unroll
            for (int k = 0; k < 4; ++k) {
                int c = sub * 4 + k;
                if (c < OBS_DIM) vv[k] = obs[row * OBS_DIM + c];
                else if (c < OBS_DIM + ACT_DIM) vv[k] = act[row * ACT_DIM + (c - OBS_DIM)];
            }
        }
        ((float4*)xpad)[i] = v;
    }
    if (i <= N_NODES) cnt[i] = 0;
    if (i < HID / 4)
        ((float4*)(y2 + (size_t)SENT * HID))[i] = make_float4(0.f, 0.f, 0.f, 0.f);
    if (i == 0) *bar = 0u;
}

// ---------------- monotone grid barrier (all GRID blocks co-resident) ----------------

__device__ __forceinline__ void gbar(unsigned* bar) {
    __syncthreads();
    if (threadIdx.x == 0) {
        __threadfence();  // release: make this block's writes visible device-wide
        unsigned v0 = __hip_atomic_fetch_add(bar, 1u, __ATOMIC_RELAXED, __HIP_MEMORY_SCOPE_AGENT);
        unsigned tgt = (v0 / (unsigned)GRID + 1u) * (unsigned)GRID;
        while (__hip_atomic_load(bar, __ATOMIC_RELAXED, __HIP_MEMORY_SCOPE_AGENT) < tgt)
            __builtin_amdgcn_s_sleep(2);
    }
    __syncthreads();
    __threadfence();  // acquire: see other blocks' writes
}

// ---------------- mega: build -> layer1(agg+W1+W2) -> agg2 -> heads ----------------

__global__ __launch_bounds__(512, 4) void k_mega(
    const int4* __restrict__ src4, const int4* __restrict__ dst4,
    int* __restrict__ cnt, int* __restrict__ col,
    const float4* __restrict__ x4, const float* __restrict__ W1, const float* __restrict__ b1,
    const float* __restrict__ W2g, float* __restrict__ dis, float* __restrict__ y2,
    const float* __restrict__ b2, float* __restrict__ h2,
    const float* __restrict__ Wq1, const float* __restrict__ Bq1,
    const float* __restrict__ w1b, const float* __restrict__ b1b,
    const float* __restrict__ Wq2, const float* __restrict__ Bq2,
    const float* __restrict__ w2b, const float* __restrict__ b2b,
    float* __restrict__ q1, float* __restrict__ q2, unsigned* __restrict__ bar) {
    __shared__ float lds[12288];          // 48 KB, phase-aliased
    __shared__ float part1[8][8], part2[8][8];
    int t = threadIdx.x;
    int bid = blockIdx.x;
    int wave = t >> 6, lane = t & 63;

    // ---- P1: ELL build (one atomic per edge reserves slot + counts degree)
    for (int i = bid * TPB + t; i < N_EDGES / 4; i += GRID * TPB) {
        int4 s = src4[i];
        int4 d = dst4[i];
        int p;
        p = atomicAdd(&cnt[d.x], 1); col[d.x * ELL_W + p] = s.x;
        p = atomicAdd(&cnt[d.y], 1); col[d.y * ELL_W + p] = s.y;
        p = atomicAdd(&cnt[d.z], 1); col[d.z * ELL_W + p] = s.z;
        p = atomicAdd(&cnt[d.w], 1); col[d.w * ELL_W + p] = s.w;
    }
    gbar(bar);

    // ---- P2: layer1 fused: z=d_i*(sum d_j x_j + d_i x_i); h1=relu(z@W1+b1); y2=dis*(h1@W2)
    {
        float* w1s = lds;          // 34*128 = 4352
        float* zs  = lds + 4352;   // 16*64  = 1024
        float* hs  = lds + 5376;   // 16*128 = 2048
        float* w2s = lds + 7424;   // 32*128 = 4096  (total 11520)
        for (int i = t; i < 1088; i += TPB) ((float4*)w1s)[i] = ((const float4*)W1)[i];
        int g = lane >> 4, sub = lane & 15;
        float bb0 = b1[lane], bb64 = b1[lane + 64];
        for (int grp = bid; grp < 625; grp += GRID) {
            __syncthreads();  // w1s ready (1st iter); hs/w2s reuse safe (later iters)
#pragma unroll
            for (int i = 0; i < 2; ++i) {
                int loc = wave * 2 + i;
                int node = grp * 16 + loc;
                int deg = cnt[node];
                float di = rsqrtf((float)(deg + 1));
                const int* cp = col + node * ELL_W;
                float4 a = make_float4(0.f, 0.f, 0.f, 0.f);
                if (g == 0) {
                    float4 xv = x4[node * 16 + sub];
                    a.x = di * xv.x; a.y = di * xv.y; a.z = di * xv.z; a.w = di * xv.w;
                }
                for (int e = 0; e < deg; e += 8) {
                    int s0 = e + g, s1 = e + 4 + g;
                    int j0 = (s0 < deg) ? cp[s0] : SENT;  // cnt[SENT]=0, x4[SENT]=0
                    int j1 = (s1 < deg) ? cp[s1] : SENT;
                    float d0 = rsqrtf((float)(cnt[j0] + 1));
                    float d1 = rsqrtf((float)(cnt[j1] + 1));
                    float4 v0 = x4[j0 * 16 + sub];
                    float4 v1 = x4[j1 * 16 + sub];
                    a.x += d0 * v0.x + d1 * v1.x;
                    a.y += d0 * v0.y + d1 * v1.y;
                    a.z += d0 * v0.z + d1 * v1.z;
                    a.w += d0 * v0.w + d1 * v1.w;
                }
                a.x += __shfl_xor(a.x, 16); a.x += __shfl_xor(a.x, 32);
                a.y += __shfl_xor(a.y, 16); a.y += __shfl_xor(a.y, 32);
                a.z += __shfl_xor(a.z, 16); a.z += __shfl_xor(a.z, 32);
                a.w += __shfl_xor(a.w, 16); a.w += __shfl_xor(a.w, 32);
                if (g == 0) {
                    float4 z;
                    z.x = di * a.x; z.y = di * a.y; z.z = di * a.z; z.w = di * a.w;
                    *(float4*)&zs[loc * 64 + sub * 4] = z;
                }
                if (lane == 0) dis[node] = di;
                // per-wave GEMV h1 = relu(z@W1+b1)  (zs same-wave write/read)
                float h0 = bb0, h64 = bb64;
#pragma unroll
                for (int k = 0; k < 34; ++k) {
                    float zk = zs[loc * 64 + k];
                    h0 += zk * w1s[k * 128 + lane];
                    h64 += zk * w1s[k * 128 + 64 + lane];
                }
                hs[loc * 128 + lane] = fmaxf(h0, 0.0f);
                hs[loc * 128 + 64 + lane] = fmaxf(h64, 0.0f);
            }
            // block GEMM: y2[16x128] = dis * (hs @ W2)
            int c = t & 127, q = t >> 7;
            float acc[4] = {0, 0, 0, 0};
            for (int ch = 0; ch < 4; ++ch) {
                __syncthreads();
                for (int i = t; i < 1024; i += TPB)
                    ((float4*)w2s)[i] = ((const float4*)(W2g + ch * 4096))[i];
                __syncthreads();
                for (int k = 0; k < 32; ++k) {
                    float wv = w2s[k * 128 + c];
#pragma unroll
                    for (int r = 0; r < 4; ++r)
                        acc[r] += hs[(q * 4 + r) * 128 + ch * 32 + k] * wv;
                }
            }
#pragma unroll
            for (int r = 0; r < 4; ++r) {
                int row = grp * 16 + q * 4 + r;
                y2[row * 128 + c] = dis[row] * acc[r];
            }
        }
    }
    gbar(bar);

    // ---- P3: agg2: h2 = relu(dis_i*(sum_j y2_j + y2_i) + b2)
    {
        int half = lane >> 5, sub = lane & 31;
        const float4* y4 = (const float4*)y2;
        for (int node = bid * 8 + wave; node < N_NODES; node += GRID * 8) {
            int deg = cnt[node];
            const int* cp = col + node * ELL_W;
            float4 a = make_float4(0.f, 0.f, 0.f, 0.f);
            if (!half) a = y4[node * 32 + sub];
            for (int e = 0; e < deg; e += 8) {
                int s0 = e + half, s1 = e + 2 + half, s2 = e + 4 + half, s3 = e + 6 + half;
                int j0 = (s0 < deg) ? cp[s0] : SENT;  // y2[SENT] row = 0
                int j1 = (s1 < deg) ? cp[s1] : SENT;
                int j2 = (s2 < deg) ? cp[s2] : SENT;
                int j3 = (s3 < deg) ? cp[s3] : SENT;
                float4 v0 = y4[j0 * 32 + sub];
                float4 v1 = y4[j1 * 32 + sub];
                float4 v2 = y4[j2 * 32 + sub];
                float4 v3 = y4[j3 * 32 + sub];
                a.x += (v0.x + v1.x) + (v2.x + v3.x);
                a.y += (v0.y + v1.y) + (v2.y + v3.y);
                a.z += (v0.z + v1.z) + (v2.z + v3.z);
                a.w += (v0.w + v1.w) + (v2.w + v3.w);
            }
            a.x += __shfl_xor(a.x, 32);
            a.y += __shfl_xor(a.y, 32);
            a.z += __shfl_xor(a.z, 32);
            a.w += __shfl_xor(a.w, 32);
            if (!half) {
                float dn = dis[node];
                float4 b = ((const float4*)b2)[sub];
                float4 r;
                r.x = fmaxf(dn * a.x + b.x, 0.0f);
                r.y = fmaxf(dn * a.y + b.y, 0.0f);
                r.z = fmaxf(dn * a.z + b.z, 0.0f);
                r.w = fmaxf(dn * a.w + b.w, 0.0f);
                ((float4*)h2)[node * 32 + sub] = r;
            }
        }
    }
    gbar(bar);

    // ---- P4: heads: q = relu(h2@Wq+Bq) . wb + bb  (32 rows/block, 313 groups)
    {
        float* xs  = lds;           // 32*128 = 4096
        float* w1h = lds + 4096;    // 4096
        float* w2h = lds + 8192;    // 4096
        for (int grp = bid; grp < 313; grp += GRID) {
            __syncthreads();
            for (int i = t; i < 1024; i += TPB) {
                int row = grp * 32 + (i >> 5);
                int rr = (row < N_NODES) ? row : (N_NODES - 1);
                ((float4*)xs)[i] = ((const float4*)h2)[rr * 32 + (i & 31)];
            }
            int c = t & 127, q = t >> 7;
            float a1[8] = {0, 0, 0, 0, 0, 0, 0, 0};
            float a2[8] = {0, 0, 0, 0, 0, 0, 0, 0};
            for (int ch = 0; ch < 4; ++ch) {
                __syncthreads();
                for (int i = t; i < 1024; i += TPB) {
                    ((float4*)w1h)[i] = ((const float4*)(Wq1 + ch * 4096))[i];
                    ((float4*)w2h)[i] = ((const float4*)(Wq2 + ch * 4096))[i];
                }
                __syncthreads();
                for (int k = 0; k < 32; ++k) {
                    float wv1 = w1h[k * 128 + c];
                    float wv2 = w2h[k * 128 + c];
#pragma unroll
                    for (int r = 0; r < 8; ++r) {
                        float xv = xs[(q * 8 + r) * 128 + ch * 32 + k];
                        a1[r] += xv * wv1;
                        a2[r] += xv * wv2;
                    }
                }
            }
            float bb1 = Bq1[c], bb2 = Bq2[c];
            float v1 = w1b[c], v2 = w2b[c];
            float s1[8], s2[8];
#pragma unroll
            for (int r = 0; r < 8; ++r) {
                s1[r] = fmaxf(a1[r] + bb1, 0.0f) * v1;
                s2[r] = fmaxf(a2[r] + bb2, 0.0f) * v2;
            }
#pragma unroll
            for (int off = 1; off < 64; off <<= 1) {
#pragma unroll
                for (int r = 0; r < 8; ++r) {
                    s1[r] += __shfl_xor(s1[r], off);
                    s2[r] += __shfl_xor(s2[r], off);
                }
            }
            if (lane == 0) {
#pragma unroll
                for (int r = 0; r < 8; ++r) {
                    part1[wave][r] = s1[r];
                    part2[wave][r] = s2[r];
                }
            }
            __syncthreads();
            if (t < 32) {
                int qq = t >> 3, r = t & 7;
                int row = grp * 32 + t;
                if (row < N_NODES) {
                    q1[row] = part1[2 * qq][r] + part1[2 * qq + 1][r] + b1b[0];
                    q2[row] = part2[2 * qq][r] + part2[2 * qq + 1][r] + b2b[0];
                }
            }
        }
    }
}

extern "C" void kernel_launch(void* const* d_in, const int* in_sizes, int n_in,
                              void* d_out, int out_size, void* d_ws, size_t ws_size,
                              hipStream_t stream) {
    (void)in_sizes; (void)n_in; (void)out_size; (void)ws_size;
    const float* obs  = (const float*)d_in[0];
    const float* act  = (const float*)d_in[1];
    const int*   ei   = (const int*)d_in[2];
    const int*   src  = ei;
    const int*   dst  = ei + N_EDGES;
    const float* w_g1 = (const float*)d_in[3];
    const float* b_g1 = (const float*)d_in[4];
    const float* w_g2 = (const float*)d_in[5];
    const float* b_g2 = (const float*)d_in[6];
    const float* w_q1a = (const float*)d_in[7];
    const float* b_q1a = (const float*)d_in[8];
    const float* w_q1b = (const float*)d_in[9];
    const float* b_q1b = (const float*)d_in[10];
    const float* w_q2a = (const float*)d_in[11];
    const float* b_q2a = (const float*)d_in[12];
    const float* w_q2b = (const float*)d_in[13];
    const float* b_q2b = (const float*)d_in[14];
    float* out = (float*)d_out;

    char* ws = (char*)d_ws;
    size_t off = 0;
    auto alloc = [&](size_t bytes) {
        void* p = ws + off;
        off = (off + bytes + 255) & ~(size_t)255;
        return p;
    };
    int*      cnt  = (int*)alloc((N_NODES + 1) * 4);
    float*    dis  = (float*)alloc(N_NODES * 4);
    unsigned* bar  = (unsigned*)alloc(256);
    int*      col  = (int*)alloc((size_t)N_NODES * ELL_W * 4);
    float*    xpad = (float*)alloc((size_t)(N_NODES + 1) * 64 * 4);
    float*    y2b  = (float*)alloc((size_t)(N_NODES + 1) * HID * 4);  // +sentinel row
    float*    h2b  = (float*)alloc((size_t)N_NODES * HID * 4);

    k_init<<<((N_NODES + 1) * 16 + 255) / 256, 256, 0, stream>>>(cnt, bar, xpad, y2b, obs, act);
    k_mega<<<GRID, TPB, 0, stream>>>(
        (const int4*)src, (const int4*)dst, cnt, col,
        (const float4*)xpad, w_g1, b_g1,
        w_g2, dis, y2b,
        b_g2, h2b,
        w_q1a, b_q1a, w_q1b, b_q1b,
        w_q2a, b_q2a, w_q2b, b_q2b,
        out, out + N_NODES, bar);
}

// Round 9
// 641.617 us; speedup vs baseline: 1.6857x; 1.6857x over previous
//
#include <hip/hip_runtime.h>

#define N_NODES 10000
#define N_EDGES 320000
#define OBS_DIM 30
#define ACT_DIM 4
#define HID 128
#define ELL_W 96   // padded neighbor-list width; deg ~Poisson(32), P(deg>88) ~ 1e-12
#define SENT N_NODES
#define GRID 512   // co-resident: 2 blocks/CU x 256 CU; LDS 46.5KB <= 80KB/block
#define TPB 256

// ---------------- init: cnt=0, bar=0, xpad rows (obs|act|0)+zero sentinel, y2 sentinel=0

__global__ __launch_bounds__(256) void k_init(int* __restrict__ cnt,
                                              unsigned* __restrict__ bar,
                                              float* __restrict__ xpad,
                                              float* __restrict__ y2,
                                              const float* __restrict__ obs,
                                              const float* __restrict__ act) {
    int i = blockIdx.x * 256 + threadIdx.x;
    if (i < (N_NODES + 1) * 16) {
        int row = i >> 4, sub = i & 15;
        float4 v = make_float4(0.f, 0.f, 0.f, 0.f);
        if (row < N_NODES) {
            float* vv = &v.x;
#pragma unroll
            for (int k = 0; k < 4; ++k) {
                int c = sub * 4 + k;
                if (c < OBS_DIM) vv[k] = obs[row * OBS_DIM + c];
                else if (c < OBS_DIM + ACT_DIM) vv[k] = act[row * ACT_DIM + (c - OBS_DIM)];
            }
        }
        ((float4*)xpad)[i] = v;
    }
    if (i <= N_NODES) cnt[i] = 0;
    if (i < HID / 4)
        ((float4*)(y2 + (size_t)SENT * HID))[i] = make_float4(0.f, 0.f, 0.f, 0.f);
    if (i == 0) *bar = 0u;
}

// ---------------- monotone grid barrier (all GRID blocks co-resident) ----------------

__device__ __forceinline__ void gbar(unsigned* bar) {
    __syncthreads();
    if (threadIdx.x == 0) {
        __threadfence();  // release: flush this block's writes device-wide
        unsigned v0 = __hip_atomic_fetch_add(bar, 1u, __ATOMIC_RELAXED, __HIP_MEMORY_SCOPE_AGENT);
        unsigned tgt = (v0 / (unsigned)GRID + 1u) * (unsigned)GRID;
        while (__hip_atomic_load(bar, __ATOMIC_RELAXED, __HIP_MEMORY_SCOPE_AGENT) < tgt)
            __builtin_amdgcn_s_sleep(2);
    }
    __syncthreads();
    __threadfence();  // acquire: see other blocks' writes
}

// ---------------- mega: build -> layer1(agg+W1+W2) -> agg2 -> heads ----------------

__global__ __launch_bounds__(256, 2) void k_mega(
    const int4* __restrict__ src4, const int4* __restrict__ dst4,
    int* __restrict__ cnt, int* __restrict__ col,
    const float4* __restrict__ x4, const float* __restrict__ W1, const float* __restrict__ b1,
    const float* __restrict__ W2g, float* __restrict__ y2,
    const float* __restrict__ b2, float* __restrict__ h2,
    const float* __restrict__ Wq1, const float* __restrict__ Bq1,
    const float* __restrict__ w1b, const float* __restrict__ b1b,
    const float* __restrict__ Wq2, const float* __restrict__ Bq2,
    const float* __restrict__ w2b, const float* __restrict__ b2b,
    float* __restrict__ q1, float* __restrict__ q2, unsigned* __restrict__ bar) {
    __shared__ float lds[11520];          // 46 KB, phase-aliased
    __shared__ float part1[4][8], part2[4][8];
    int t = threadIdx.x;
    int bid = blockIdx.x;
    int wave = t >> 6, lane = t & 63;

    // ---- P1: ELL build (one atomic per edge reserves slot + counts degree)
    for (int i = bid * TPB + t; i < N_EDGES / 4; i += GRID * TPB) {
        int4 s = src4[i];
        int4 d = dst4[i];
        int p;
        p = atomicAdd(&cnt[d.x], 1); col[d.x * ELL_W + p] = s.x;
        p = atomicAdd(&cnt[d.y], 1); col[d.y * ELL_W + p] = s.y;
        p = atomicAdd(&cnt[d.z], 1); col[d.z * ELL_W + p] = s.z;
        p = atomicAdd(&cnt[d.w], 1); col[d.w * ELL_W + p] = s.w;
    }
    gbar(bar);

    // ---- P2: layer1 fused: z=d_i*(sum d_j x_j + d_i x_i); h1=relu(z@W1+b1); y2=dis*(h1@W2)
    {
        float* w1s = lds;          // 34*128 = 4352
        float* zs  = lds + 4352;   // 16*64  = 1024
        float* hs  = lds + 5376;   // 16*128 = 2048
        float* w2s = lds + 7424;   // 32*128 = 4096  (total 11520)
        for (int i = t; i < 1088; i += TPB) ((float4*)w1s)[i] = ((const float4*)W1)[i];
        int g = lane >> 4, sub = lane & 15;
        float bb0 = b1[lane], bb64 = b1[lane + 64];
        for (int grp = bid; grp < 625; grp += GRID) {
            __syncthreads();  // w1s ready (1st iter); hs/w2s reuse safe (later iters)
#pragma unroll
            for (int i = 0; i < 4; ++i) {
                int loc = wave * 4 + i;
                int node = grp * 16 + loc;
                int deg = cnt[node];
                float di = rsqrtf((float)(deg + 1));
                const int* cp = col + node * ELL_W;
                float4 a = make_float4(0.f, 0.f, 0.f, 0.f);
                if (g == 0) {
                    float4 xv = x4[node * 16 + sub];
                    a.x = di * xv.x; a.y = di * xv.y; a.z = di * xv.z; a.w = di * xv.w;
                }
                for (int e = 0; e < deg; e += 8) {
                    int s0 = e + g, s1 = e + 4 + g;
                    int j0 = (s0 < deg) ? cp[s0] : SENT;  // cnt[SENT]=0, x4[SENT]=0
                    int j1 = (s1 < deg) ? cp[s1] : SENT;
                    float d0 = rsqrtf((float)(cnt[j0] + 1));
                    float d1 = rsqrtf((float)(cnt[j1] + 1));
                    float4 v0 = x4[j0 * 16 + sub];
                    float4 v1 = x4[j1 * 16 + sub];
                    a.x += d0 * v0.x + d1 * v1.x;
                    a.y += d0 * v0.y + d1 * v1.y;
                    a.z += d0 * v0.z + d1 * v1.z;
                    a.w += d0 * v0.w + d1 * v1.w;
                }
                a.x += __shfl_xor(a.x, 16); a.x += __shfl_xor(a.x, 32);
                a.y += __shfl_xor(a.y, 16); a.y += __shfl_xor(a.y, 32);
                a.z += __shfl_xor(a.z, 16); a.z += __shfl_xor(a.z, 32);
                a.w += __shfl_xor(a.w, 16); a.w += __shfl_xor(a.w, 32);
                if (g == 0) {
                    float4 z;
                    z.x = di * a.x; z.y = di * a.y; z.z = di * a.z; z.w = di * a.w;
                    *(float4*)&zs[loc * 64 + sub * 4] = z;
                }
                // per-wave GEMV h1 = relu(z@W1+b1)  (zs same-wave write/read)
                float h0 = bb0, h64 = bb64;
#pragma unroll
                for (int k = 0; k < 34; ++k) {
                    float zk = zs[loc * 64 + k];
                    h0 += zk * w1s[k * 128 + lane];
                    h64 += zk * w1s[k * 128 + 64 + lane];
                }
                hs[loc * 128 + lane] = fmaxf(h0, 0.0f);
                hs[loc * 128 + 64 + lane] = fmaxf(h64, 0.0f);
            }
            // block GEMM: y2[16x128] = rsqrt(cnt+1) * (hs @ W2)
            int c = t & 127, q = t >> 7;
            float acc[8] = {0, 0, 0, 0, 0, 0, 0, 0};
            for (int ch = 0; ch < 4; ++ch) {
                __syncthreads();
                for (int i = t; i < 1024; i += TPB)
                    ((float4*)w2s)[i] = ((const float4*)(W2g + ch * 4096))[i];
                __syncthreads();
                for (int k = 0; k < 32; ++k) {
                    float wv = w2s[k * 128 + c];
#pragma unroll
                    for (int r = 0; r < 8; ++r)
                        acc[r] += hs[(q * 8 + r) * 128 + ch * 32 + k] * wv;
                }
            }
#pragma unroll
            for (int r = 0; r < 8; ++r) {
                int row = grp * 16 + q * 8 + r;
                float dr = rsqrtf((float)(cnt[row] + 1));
                y2[row * 128 + c] = dr * acc[r];
            }
        }
    }
    gbar(bar);

    // ---- P3: agg2: h2 = relu(dis_i*(sum_j y2_j + y2_i) + b2)
    {
        int half = lane >> 5, sub = lane & 31;
        const float4* y4 = (const float4*)y2;
        for (int node = bid * 4 + wave; node < N_NODES; node += GRID * 4) {
            int deg = cnt[node];
            const int* cp = col + node * ELL_W;
            float4 a = make_float4(0.f, 0.f, 0.f, 0.f);
            if (!half) a = y4[node * 32 + sub];
            for (int e = 0; e < deg; e += 8) {
                int s0 = e + half, s1 = e + 2 + half, s2 = e + 4 + half, s3 = e + 6 + half;
                int j0 = (s0 < deg) ? cp[s0] : SENT;  // y2[SENT] row = 0
                int j1 = (s1 < deg) ? cp[s1] : SENT;
                int j2 = (s2 < deg) ? cp[s2] : SENT;
                int j3 = (s3 < deg) ? cp[s3] : SENT;
                float4 v0 = y4[j0 * 32 + sub];
                float4 v1 = y4[j1 * 32 + sub];
                float4 v2 = y4[j2 * 32 + sub];
                float4 v3 = y4[j3 * 32 + sub];
                a.x += (v0.x + v1.x) + (v2.x + v3.x);
                a.y += (v0.y + v1.y) + (v2.y + v3.y);
                a.z += (v0.z + v1.z) + (v2.z + v3.z);
                a.w += (v0.w + v1.w) + (v2.w + v3.w);
            }
            a.x += __shfl_xor(a.x, 32);
            a.y += __shfl_xor(a.y, 32);
            a.z += __shfl_xor(a.z, 32);
            a.w += __shfl_xor(a.w, 32);
            if (!half) {
                float dn = rsqrtf((float)(deg + 1));
                float4 b = ((const float4*)b2)[sub];
                float4 r;
                r.x = fmaxf(dn * a.x + b.x, 0.0f);
                r.y = fmaxf(dn * a.y + b.y, 0.0f);
                r.z = fmaxf(dn * a.z + b.z, 0.0f);
                r.w = fmaxf(dn * a.w + b.w, 0.0f);
                ((float4*)h2)[node * 32 + sub] = r;
            }
        }
    }
    gbar(bar);

    // ---- P4: heads: q = relu(h2@Wq+Bq) . wb + bb  (16 rows/group, 625 groups)
    {
        float* xs  = lds;           // 16*128 = 2048
        float* w1h = lds + 2048;    // 4096
        float* w2h = lds + 6144;    // 4096
        for (int grp = bid; grp < 625; grp += GRID) {
            __syncthreads();  // guard xs/part reuse across grp iterations
            for (int i = t; i < 512; i += TPB)
                ((float4*)xs)[i] = ((const float4*)h2)[grp * 512 + i];
            int c = t & 127, q = t >> 7;
            float a1[8] = {0, 0, 0, 0, 0, 0, 0, 0};
            float a2[8] = {0, 0, 0, 0, 0, 0, 0, 0};
            for (int ch = 0; ch < 4; ++ch) {
                __syncthreads();
                for (int i = t; i < 1024; i += TPB) {
                    ((float4*)w1h)[i] = ((const float4*)(Wq1 + ch * 4096))[i];
                    ((float4*)w2h)[i] = ((const float4*)(Wq2 + ch * 4096))[i];
                }
                __syncthreads();
                for (int k = 0; k < 32; ++k) {
                    float wv1 = w1h[k * 128 + c];
                    float wv2 = w2h[k * 128 + c];
#pragma unroll
                    for (int r = 0; r < 8; ++r) {
                        float xv = xs[(q * 8 + r) * 128 + ch * 32 + k];
                        a1[r] += xv * wv1;
                        a2[r] += xv * wv2;
                    }
                }
            }
            float bb1 = Bq1[c], bb2 = Bq2[c];
            float v1 = w1b[c], v2 = w2b[c];
            float s1[8], s2[8];
#pragma unroll
            for (int r = 0; r < 8; ++r) {
                s1[r] = fmaxf(a1[r] + bb1, 0.0f) * v1;
                s2[r] = fmaxf(a2[r] + bb2, 0.0f) * v2;
            }
#pragma unroll
            for (int off = 1; off < 64; off <<= 1) {
#pragma unroll
                for (int r = 0; r < 8; ++r) {
                    s1[r] += __shfl_xor(s1[r], off);
                    s2[r] += __shfl_xor(s2[r], off);
                }
            }
            if (lane == 0) {
#pragma unroll
                for (int r = 0; r < 8; ++r) {
                    part1[wave][r] = s1[r];
                    part2[wave][r] = s2[r];
                }
            }
            __syncthreads();
            if (t < 16) {
                int hf = t >> 3, r = t & 7;
                int row = grp * 16 + hf * 8 + r;
                q1[row] = part1[hf * 2][r] + part1[hf * 2 + 1][r] + b1b[0];
                q2[row] = part2[hf * 2][r] + part2[hf * 2 + 1][r] + b2b[0];
            }
        }
    }
}

extern "C" void kernel_launch(void* const* d_in, const int* in_sizes, int n_in,
                              void* d_out, int out_size, void* d_ws, size_t ws_size,
                              hipStream_t stream) {
    (void)in_sizes; (void)n_in; (void)out_size; (void)ws_size;
    const float* obs  = (const float*)d_in[0];
    const float* act  = (const float*)d_in[1];
    const int*   ei   = (const int*)d_in[2];
    const int*   src  = ei;
    const int*   dst  = ei + N_EDGES;
    const float* w_g1 = (const float*)d_in[3];
    const float* b_g1 = (const float*)d_in[4];
    const float* w_g2 = (const float*)d_in[5];
    const float* b_g2 = (const float*)d_in[6];
    const float* w_q1a = (const float*)d_in[7];
    const float* b_q1a = (const float*)d_in[8];
    const float* w_q1b = (const float*)d_in[9];
    const float* b_q1b = (const float*)d_in[10];
    const float* w_q2a = (const float*)d_in[11];
    const float* b_q2a = (const float*)d_in[12];
    const float* w_q2b = (const float*)d_in[13];
    const float* b_q2b = (const float*)d_in[14];
    float* out = (float*)d_out;

    char* ws = (char*)d_ws;
    size_t off = 0;
    auto alloc = [&](size_t bytes) {
        void* p = ws + off;
        off = (off + bytes + 255) & ~(size_t)255;
        return p;
    };
    int*      cnt  = (int*)alloc((N_NODES + 1) * 4);
    unsigned* bar  = (unsigned*)alloc(256);
    int*      col  = (int*)alloc((size_t)N_NODES * ELL_W * 4);
    float*    xpad = (float*)alloc((size_t)(N_NODES + 1) * 64 * 4);
    float*    y2b  = (float*)alloc((size_t)(N_NODES + 1) * HID * 4);  // +sentinel row
    float*    h2b  = (float*)alloc((size_t)N_NODES * HID * 4);

    k_init<<<((N_NODES + 1) * 16 + 255) / 256, 256, 0, stream>>>(cnt, bar, xpad, y2b, obs, act);
    k_mega<<<GRID, TPB, 0, stream>>>(
        (const int4*)src, (const int4*)dst, cnt, col,
        (const float4*)xpad, w_g1, b_g1,
        w_g2, y2b,
        b_g2, h2b,
        w_q1a, b_q1a, w_q1b, b_q1b,
        w_q2a, b_q2a, w_q2b, b_q2b,
        out, out + N_NODES, bar);
}

// Round 10
// 154.029 us; speedup vs baseline: 7.0219x; 4.1656x over previous
//
#include <hip/hip_runtime.h>

#define N_NODES 10000
#define N_EDGES 320000
#define OBS_DIM 30
#define ACT_DIM 4
#define HID 128
#define ELL_W 96   // padded neighbor-list width; deg ~Poisson(32), P(deg>88) ~ 1e-12
#define SENT N_NODES

// ---------------- init: cnt=0, xpad rows (obs|act|0)+zero sentinel, y2 sentinel=0

__global__ __launch_bounds__(256) void k_init(int* __restrict__ cnt,
                                              float* __restrict__ xpad,
                                              float* __restrict__ y2,
                                              const float* __restrict__ obs,
                                              const float* __restrict__ act) {
    int i = blockIdx.x * 256 + threadIdx.x;
    if (i < (N_NODES + 1) * 16) {
        int row = i >> 4, sub = i & 15;
        float4 v = make_float4(0.f, 0.f, 0.f, 0.f);
        if (row < N_NODES) {
            float* vv = &v.x;
#pragma unroll
            for (int k = 0; k < 4; ++k) {
                int c = sub * 4 + k;
                if (c < OBS_DIM) vv[k] = obs[row * OBS_DIM + c];
                else if (c < OBS_DIM + ACT_DIM) vv[k] = act[row * ACT_DIM + (c - OBS_DIM)];
            }
        }
        ((float4*)xpad)[i] = v;
    }
    if (i <= N_NODES) cnt[i] = 0;
    if (i < HID / 4)
        ((float4*)(y2 + (size_t)SENT * HID))[i] = make_float4(0.f, 0.f, 0.f, 0.f);
}

// ---------------- build: one atomic per edge reserves ELL slot AND counts degree ----------------

__global__ __launch_bounds__(256) void k_build(const int4* __restrict__ src4,
                                               const int4* __restrict__ dst4,
                                               int* __restrict__ cnt,
                                               int* __restrict__ col) {
    int i = blockIdx.x * 256 + threadIdx.x;
    if (i < N_EDGES / 4) {
        int4 s = src4[i];
        int4 d = dst4[i];
        int p;
        p = atomicAdd(&cnt[d.x], 1); col[d.x * ELL_W + p] = s.x;
        p = atomicAdd(&cnt[d.y], 1); col[d.y * ELL_W + p] = s.y;
        p = atomicAdd(&cnt[d.z], 1); col[d.z * ELL_W + p] = s.z;
        p = atomicAdd(&cnt[d.w], 1); col[d.w * ELL_W + p] = s.w;
    }
}

// ---------------- layer1: z=d_i*(sum d_j x_j + d_i x_i); h1=relu(z@W1+b1); y2=d_i*(h1@W2)
// 1250 blocks x 8 nodes (4 waves, 2 nodes/wave); W1 GEMV per-wave; W2 GEMM per-block.

__global__ __launch_bounds__(256) void k_layer1(const float4* __restrict__ x4,
                                                const int* __restrict__ cnt,
                                                const int* __restrict__ col,
                                                const float* __restrict__ W1,
                                                const float* __restrict__ b1,
                                                const float* __restrict__ W2g,
                                                float* __restrict__ y2) {
    __shared__ float w1s[34 * 128];   // 4352
    __shared__ float zs[8][64];       // 512
    __shared__ float hs[8 * 128];     // 1024
    __shared__ float w2s[32 * 128];   // 4096  -> total ~40 KB
    int t = threadIdx.x;
    int bid = blockIdx.x;
    int wave = t >> 6, lane = t & 63, g = lane >> 4, sub = lane & 15;
    {
        float4* wsp = (float4*)w1s;
        const float4* Wp = (const float4*)W1;
        for (int i = t; i < 1088; i += 256) wsp[i] = Wp[i];
    }
    float bb0 = b1[lane], bb64 = b1[lane + 64];
#pragma unroll
    for (int i = 0; i < 2; ++i) {
        int loc = wave * 2 + i;
        int node = bid * 8 + loc;
        int deg = cnt[node];
        float di = rsqrtf((float)(deg + 1));
        const int* cp = col + node * ELL_W;
        float4 a = make_float4(0.f, 0.f, 0.f, 0.f);
        if (g == 0) {
            float4 xv = x4[node * 16 + sub];
            a.x = di * xv.x; a.y = di * xv.y; a.z = di * xv.z; a.w = di * xv.w;
        }
        for (int e = 0; e < deg; e += 8) {
            int s0 = e + g, s1 = e + 4 + g;
            int j0 = (s0 < deg) ? cp[s0] : SENT;  // cnt[SENT]=0 -> d=1; x4[SENT]=0
            int j1 = (s1 < deg) ? cp[s1] : SENT;
            float d0 = rsqrtf((float)(cnt[j0] + 1));
            float d1 = rsqrtf((float)(cnt[j1] + 1));
            float4 v0 = x4[j0 * 16 + sub];
            float4 v1 = x4[j1 * 16 + sub];
            a.x += d0 * v0.x + d1 * v1.x;
            a.y += d0 * v0.y + d1 * v1.y;
            a.z += d0 * v0.z + d1 * v1.z;
            a.w += d0 * v0.w + d1 * v1.w;
        }
        a.x += __shfl_xor(a.x, 16); a.x += __shfl_xor(a.x, 32);
        a.y += __shfl_xor(a.y, 16); a.y += __shfl_xor(a.y, 32);
        a.z += __shfl_xor(a.z, 16); a.z += __shfl_xor(a.z, 32);
        a.w += __shfl_xor(a.w, 16); a.w += __shfl_xor(a.w, 32);
        if (g == 0) {
            float4 z;
            z.x = di * a.x; z.y = di * a.y; z.z = di * a.z; z.w = di * a.w;
            *(float4*)&zs[loc][sub * 4] = z;
        }
        // per-wave GEMV h1 = relu(z@W1+b1); w1s load guarded by same-wave lgkmcnt +
        // cross-wave: every wave loaded a disjoint 1/4 of w1s... need barrier for w1s!
        __syncthreads();  // w1s complete (no-op cost beyond first iteration)
        float h0 = bb0, h64 = bb64;
#pragma unroll
        for (int k = 0; k < 34; ++k) {
            float zk = zs[loc][k];
            h0 += zk * w1s[k * 128 + lane];
            h64 += zk * w1s[k * 128 + 64 + lane];
        }
        hs[loc * 128 + lane] = fmaxf(h0, 0.0f);
        hs[loc * 128 + 64 + lane] = fmaxf(h64, 0.0f);
    }
    // block GEMM: y2[8x128] = rsqrt(cnt+1) * (hs @ W2)
    int c = t & 127, q = t >> 7;
    float acc[4] = {0, 0, 0, 0};
    for (int ch = 0; ch < 4; ++ch) {
        __syncthreads();  // first iter: hs complete; later: w2s reuse safe
        {
            float4* wsp = (float4*)w2s;
            const float4* Wp = (const float4*)(W2g + ch * 4096);
            for (int i = t; i < 1024; i += 256) wsp[i] = Wp[i];
        }
        __syncthreads();
        for (int k = 0; k < 32; ++k) {
            float wv = w2s[k * 128 + c];
#pragma unroll
            for (int r = 0; r < 4; ++r)
                acc[r] += hs[(q * 4 + r) * 128 + ch * 32 + k] * wv;
        }
    }
#pragma unroll
    for (int r = 0; r < 4; ++r) {
        int row = bid * 8 + q * 4 + r;
        float dr = rsqrtf((float)(cnt[row] + 1));
        y2[row * 128 + c] = dr * acc[r];
    }
}

// ---------------- layer2: h2=relu(d_i*(sum y2_j + y2_i)+b2) [gather->LDS];
//                  q = relu(h2@Wq+Bq) . wb + bb  (both heads, block GEMM epilogue)
// 625 blocks x 16 nodes (4 waves, 4 nodes/wave).

__global__ __launch_bounds__(256) void k_layer2(const float4* __restrict__ y4,
                                                const int* __restrict__ cnt,
                                                const int* __restrict__ col,
                                                const float* __restrict__ b2,
                                                const float* __restrict__ Wq1, const float* __restrict__ Bq1,
                                                const float* __restrict__ w1b, const float* __restrict__ b1b,
                                                const float* __restrict__ Wq2, const float* __restrict__ Bq2,
                                                const float* __restrict__ w2b, const float* __restrict__ b2b,
                                                float* __restrict__ q1, float* __restrict__ q2) {
    __shared__ float hs[16 * 128];    // 2048
    __shared__ float w1h[32 * 128];   // 4096
    __shared__ float w2h[32 * 128];   // 4096  -> ~41 KB
    __shared__ float part1[4][8], part2[4][8];
    int t = threadIdx.x;
    int bid = blockIdx.x;
    int wave = t >> 6, lane = t & 63, half = lane >> 5, sub = lane & 31;
#pragma unroll
    for (int i = 0; i < 4; ++i) {
        int loc = wave * 4 + i;
        int node = bid * 16 + loc;
        int deg = cnt[node];
        const int* cp = col + node * ELL_W;
        float4 a = make_float4(0.f, 0.f, 0.f, 0.f);
        if (!half) a = y4[node * 32 + sub];  // self-loop term
        for (int e = 0; e < deg; e += 8) {
            int s0 = e + half, s1 = e + 2 + half, s2 = e + 4 + half, s3 = e + 6 + half;
            int j0 = (s0 < deg) ? cp[s0] : SENT;  // y2[SENT] row = 0
            int j1 = (s1 < deg) ? cp[s1] : SENT;
            int j2 = (s2 < deg) ? cp[s2] : SENT;
            int j3 = (s3 < deg) ? cp[s3] : SENT;
            float4 v0 = y4[j0 * 32 + sub];
            float4 v1 = y4[j1 * 32 + sub];
            float4 v2 = y4[j2 * 32 + sub];
            float4 v3 = y4[j3 * 32 + sub];
            a.x += (v0.x + v1.x) + (v2.x + v3.x);
            a.y += (v0.y + v1.y) + (v2.y + v3.y);
            a.z += (v0.z + v1.z) + (v2.z + v3.z);
            a.w += (v0.w + v1.w) + (v2.w + v3.w);
        }
        a.x += __shfl_xor(a.x, 32);
        a.y += __shfl_xor(a.y, 32);
        a.z += __shfl_xor(a.z, 32);
        a.w += __shfl_xor(a.w, 32);
        if (!half) {
            float dn = rsqrtf((float)(deg + 1));
            float4 b = ((const float4*)b2)[sub];
            float4 r;
            r.x = fmaxf(dn * a.x + b.x, 0.0f);
            r.y = fmaxf(dn * a.y + b.y, 0.0f);
            r.z = fmaxf(dn * a.z + b.z, 0.0f);
            r.w = fmaxf(dn * a.w + b.w, 0.0f);
            *(float4*)&hs[loc * 128 + sub * 4] = r;
        }
    }
    // heads block GEMM on 16 rows in hs
    int c = t & 127, q = t >> 7;
    float a1[8] = {0, 0, 0, 0, 0, 0, 0, 0};
    float a2[8] = {0, 0, 0, 0, 0, 0, 0, 0};
    for (int ch = 0; ch < 4; ++ch) {
        __syncthreads();  // first iter: hs complete; later: w*h reuse safe
        for (int i = t; i < 1024; i += 256) {
            ((float4*)w1h)[i] = ((const float4*)(Wq1 + ch * 4096))[i];
            ((float4*)w2h)[i] = ((const float4*)(Wq2 + ch * 4096))[i];
        }
        __syncthreads();
        for (int k = 0; k < 32; ++k) {
            float wv1 = w1h[k * 128 + c];
            float wv2 = w2h[k * 128 + c];
#pragma unroll
            for (int r = 0; r < 8; ++r) {
                float xv = hs[(q * 8 + r) * 128 + ch * 32 + k];
                a1[r] += xv * wv1;
                a2[r] += xv * wv2;
            }
        }
    }
    float bb1 = Bq1[c], bb2 = Bq2[c];
    float v1 = w1b[c], v2 = w2b[c];
    float s1[8], s2[8];
#pragma unroll
    for (int r = 0; r < 8; ++r) {
        s1[r] = fmaxf(a1[r] + bb1, 0.0f) * v1;
        s2[r] = fmaxf(a2[r] + bb2, 0.0f) * v2;
    }
#pragma unroll
    for (int off = 1; off < 64; off <<= 1) {
#pragma unroll
        for (int r = 0; r < 8; ++r) {
            s1[r] += __shfl_xor(s1[r], off);
            s2[r] += __shfl_xor(s2[r], off);
        }
    }
    if (lane == 0) {
#pragma unroll
        for (int r = 0; r < 8; ++r) {
            part1[wave][r] = s1[r];
            part2[wave][r] = s2[r];
        }
    }
    __syncthreads();
    if (t < 16) {
        int hf = t >> 3, r = t & 7;
        int row = bid * 16 + hf * 8 + r;
        q1[row] = part1[hf * 2][r] + part1[hf * 2 + 1][r] + b1b[0];
        q2[row] = part2[hf * 2][r] + part2[hf * 2 + 1][r] + b2b[0];
    }
}

extern "C" void kernel_launch(void* const* d_in, const int* in_sizes, int n_in,
                              void* d_out, int out_size, void* d_ws, size_t ws_size,
                              hipStream_t stream) {
    (void)in_sizes; (void)n_in; (void)out_size; (void)ws_size;
    const float* obs  = (const float*)d_in[0];
    const float* act  = (const float*)d_in[1];
    const int*   ei   = (const int*)d_in[2];
    const int*   src  = ei;
    const int*   dst  = ei + N_EDGES;
    const float* w_g1 = (const float*)d_in[3];
    const float* b_g1 = (const float*)d_in[4];
    const float* w_g2 = (const float*)d_in[5];
    const float* b_g2 = (const float*)d_in[6];
    const float* w_q1a = (const float*)d_in[7];
    const float* b_q1a = (const float*)d_in[8];
    const float* w_q1b = (const float*)d_in[9];
    const float* b_q1b = (const float*)d_in[10];
    const float* w_q2a = (const float*)d_in[11];
    const float* b_q2a = (const float*)d_in[12];
    const float* w_q2b = (const float*)d_in[13];
    const float* b_q2b = (const float*)d_in[14];
    float* out = (float*)d_out;

    char* ws = (char*)d_ws;
    size_t off = 0;
    auto alloc = [&](size_t bytes) {
        void* p = ws + off;
        off = (off + bytes + 255) & ~(size_t)255;
        return p;
    };
    int*   cnt  = (int*)alloc((N_NODES + 1) * 4);
    int*   col  = (int*)alloc((size_t)N_NODES * ELL_W * 4);
    float* xpad = (float*)alloc((size_t)(N_NODES + 1) * 64 * 4);
    float* y2b  = (float*)alloc((size_t)(N_NODES + 1) * HID * 4);  // +sentinel row

    k_init<<<((N_NODES + 1) * 16 + 255) / 256, 256, 0, stream>>>(cnt, xpad, y2b, obs, act);
    k_build<<<(N_EDGES / 4 + 255) / 256, 256, 0, stream>>>(
        (const int4*)src, (const int4*)dst, cnt, col);
    k_layer1<<<1250, 256, 0, stream>>>((const float4*)xpad, cnt, col,
                                       w_g1, b_g1, w_g2, y2b);
    k_layer2<<<625, 256, 0, stream>>>((const float4*)y2b, cnt, col,
                                      b_g2,
                                      w_q1a, b_q1a, w_q1b, b_q1b,
                                      w_q2a, b_q2a, w_q2b, b_q2b,
                                      out, out + N_NODES);
}

// Round 11
// 115.312 us; speedup vs baseline: 9.3795x; 1.3358x over previous
//
#include <hip/hip_runtime.h>

#define N_NODES 10000
#define N_EDGES 320000
#define OBS_DIM 30
#define ACT_DIM 4
#define HID 128
#define ELL_W 96   // padded neighbor-list width; deg ~Poisson(32), P(deg>88) ~ 1e-12
#define SENT N_NODES

// ---------------- init: cnt=0, xpad rows (obs|act|0)+zero sentinel, ph1 sentinel row=0

__global__ __launch_bounds__(256) void k_init(int* __restrict__ cnt,
                                              float* __restrict__ xpad,
                                              float* __restrict__ ph1,
                                              const float* __restrict__ obs,
                                              const float* __restrict__ act) {
    int i = blockIdx.x * 256 + threadIdx.x;
    if (i < (N_NODES + 1) * 16) {
        int row = i >> 4, sub = i & 15;
        float4 v = make_float4(0.f, 0.f, 0.f, 0.f);
        if (row < N_NODES) {
            float* vv = &v.x;
#pragma unroll
            for (int k = 0; k < 4; ++k) {
                int c = sub * 4 + k;
                if (c < OBS_DIM) vv[k] = obs[row * OBS_DIM + c];
                else if (c < OBS_DIM + ACT_DIM) vv[k] = act[row * ACT_DIM + (c - OBS_DIM)];
            }
        }
        ((float4*)xpad)[i] = v;
    }
    if (i <= N_NODES) cnt[i] = 0;
    if (i < HID / 4)
        ((float4*)(ph1 + (size_t)SENT * HID))[i] = make_float4(0.f, 0.f, 0.f, 0.f);
}

// ---------------- build: one atomic per edge reserves ELL slot AND counts degree ----------------

__global__ __launch_bounds__(256) void k_build(const int4* __restrict__ src4,
                                               const int4* __restrict__ dst4,
                                               int* __restrict__ cnt,
                                               int* __restrict__ col) {
    int i = blockIdx.x * 256 + threadIdx.x;
    if (i < N_EDGES / 4) {
        int4 s = src4[i];
        int4 d = dst4[i];
        int p;
        p = atomicAdd(&cnt[d.x], 1); col[d.x * ELL_W + p] = s.x;
        p = atomicAdd(&cnt[d.y], 1); col[d.y * ELL_W + p] = s.y;
        p = atomicAdd(&cnt[d.z], 1); col[d.z * ELL_W + p] = s.z;
        p = atomicAdd(&cnt[d.w], 1); col[d.w * ELL_W + p] = s.w;
    }
}

// ---------------- l1: z_i = d_i*(sum_j d_j x_j + d_i x_i)  (34-dim gather)
//                  ph1_i = d_i * relu(z_i @ W1 + b1)   [per-wave GEMV, W1 staged once]
// 1250 blocks x 512 thr; 8 waves, 1 node/wave; 16 lanes x float4 per row.

__global__ __launch_bounds__(512) void k_l1(const float4* __restrict__ x4,
                                            const int* __restrict__ cnt,
                                            const int* __restrict__ col,
                                            const float* __restrict__ W1,
                                            const float* __restrict__ b1,
                                            float* __restrict__ ph1) {
    __shared__ float w1s[34 * 128];
    __shared__ float zs[8][64];
    int t = threadIdx.x;
    {
        float4* wsp = (float4*)w1s;
        const float4* Wp = (const float4*)W1;
        for (int i = t; i < 1088; i += 512) wsp[i] = Wp[i];
    }
    __syncthreads();
    int wave = t >> 6, lane = t & 63, g = lane >> 4, sub = lane & 15;
    int node = blockIdx.x * 8 + wave;  // 1250*8 = 10000 exactly
    int deg = cnt[node];
    float di = rsqrtf((float)(deg + 1));
    const int* cp = col + node * ELL_W;
    float4 a = make_float4(0.f, 0.f, 0.f, 0.f);
    if (g == 0) {
        float4 xv = x4[node * 16 + sub];
        a.x = di * xv.x; a.y = di * xv.y; a.z = di * xv.z; a.w = di * xv.w;
    }
    for (int e = 0; e < deg; e += 8) {
        int s0 = e + g, s1 = e + 4 + g;
        int j0 = (s0 < deg) ? cp[s0] : SENT;  // cnt[SENT]=0 -> d=1; x4[SENT]=0
        int j1 = (s1 < deg) ? cp[s1] : SENT;
        float d0 = rsqrtf((float)(cnt[j0] + 1));
        float d1 = rsqrtf((float)(cnt[j1] + 1));
        float4 v0 = x4[j0 * 16 + sub];
        float4 v1 = x4[j1 * 16 + sub];
        a.x += d0 * v0.x + d1 * v1.x;
        a.y += d0 * v0.y + d1 * v1.y;
        a.z += d0 * v0.z + d1 * v1.z;
        a.w += d0 * v0.w + d1 * v1.w;
    }
    a.x += __shfl_xor(a.x, 16); a.x += __shfl_xor(a.x, 32);
    a.y += __shfl_xor(a.y, 16); a.y += __shfl_xor(a.y, 32);
    a.z += __shfl_xor(a.z, 16); a.z += __shfl_xor(a.z, 32);
    a.w += __shfl_xor(a.w, 16); a.w += __shfl_xor(a.w, 32);
    if (g == 0) {
        float4 z;
        z.x = di * a.x; z.y = di * a.y; z.z = di * a.z; z.w = di * a.w;
        *(float4*)&zs[wave][sub * 4] = z;
    }
    // per-wave GEMV (zs same-wave write/read; compiler inserts lgkmcnt)
    float h0 = b1[lane], h64 = b1[lane + 64];
#pragma unroll
    for (int k = 0; k < 34; ++k) {
        float zk = zs[wave][k];
        h0 += zk * w1s[k * 128 + lane];
        h64 += zk * w1s[k * 128 + 64 + lane];
    }
    ph1[node * HID + lane] = di * fmaxf(h0, 0.0f);
    ph1[node * HID + 64 + lane] = di * fmaxf(h64, 0.0f);
}

// ---------------- aggW2: s_i = sum_{j in N(i)} ph1_j + ph1_i  (128-dim gather);
//                  h2_i = relu(d_i*(s_i@W2) + b2)   [per-wave GEMV, W2 staged ONCE]
// 625 blocks x 512 thr; 8 waves x 2 nodes/wave. LDS: W2 float2-paired 64KB + zs 8KB.

__global__ __launch_bounds__(512) void k_aggW2(const float4* __restrict__ ph14,
                                               const int* __restrict__ cnt,
                                               const int* __restrict__ col,
                                               const float* __restrict__ W2,
                                               const float* __restrict__ b2,
                                               float* __restrict__ h2) {
    __shared__ float2 w2p[128 * 64];  // w2p[k*64+c] = (W2[k][c], W2[k][64+c])
    __shared__ float zs[16][128];
    int t = threadIdx.x;
    for (int i = t; i < 128 * 64; i += 512) {
        int k = i >> 6, c = i & 63;
        w2p[i] = make_float2(W2[k * 128 + c], W2[k * 128 + 64 + c]);
    }
    __syncthreads();
    int wave = t >> 6, lane = t & 63, half = lane >> 5, sub = lane & 31;
    int node0 = blockIdx.x * 16 + wave * 2;
    float di[2];
#pragma unroll
    for (int n = 0; n < 2; ++n) {
        int node = node0 + n;
        int deg = cnt[node];
        di[n] = rsqrtf((float)(deg + 1));
        const int* cp = col + node * ELL_W;
        float4 a = make_float4(0.f, 0.f, 0.f, 0.f);
        if (!half) a = ph14[node * 32 + sub];  // self term (ph1 already d_i-scaled)
        for (int e = 0; e < deg; e += 8) {
            int s0 = e + half, s1 = e + 2 + half, s2 = e + 4 + half, s3 = e + 6 + half;
            int j0 = (s0 < deg) ? cp[s0] : SENT;  // ph1[SENT] row = 0
            int j1 = (s1 < deg) ? cp[s1] : SENT;
            int j2 = (s2 < deg) ? cp[s2] : SENT;
            int j3 = (s3 < deg) ? cp[s3] : SENT;
            float4 v0 = ph14[j0 * 32 + sub];
            float4 v1 = ph14[j1 * 32 + sub];
            float4 v2 = ph14[j2 * 32 + sub];
            float4 v3 = ph14[j3 * 32 + sub];
            a.x += (v0.x + v1.x) + (v2.x + v3.x);
            a.y += (v0.y + v1.y) + (v2.y + v3.y);
            a.z += (v0.z + v1.z) + (v2.z + v3.z);
            a.w += (v0.w + v1.w) + (v2.w + v3.w);
        }
        a.x += __shfl_xor(a.x, 32);
        a.y += __shfl_xor(a.y, 32);
        a.z += __shfl_xor(a.z, 32);
        a.w += __shfl_xor(a.w, 32);
        if (!half) *(float4*)&zs[wave * 2 + n][sub * 4] = a;
    }
    // dual-node per-wave GEMV sharing W2 reads (same-wave zs write/read)
    float a00 = 0.f, a01 = 0.f, a10 = 0.f, a11 = 0.f;
    for (int k4 = 0; k4 < 32; ++k4) {
        float4 s0 = *(float4*)&zs[wave * 2][k4 * 4];
        float4 s1 = *(float4*)&zs[wave * 2 + 1][k4 * 4];
#pragma unroll
        for (int j = 0; j < 4; ++j) {
            float2 w = w2p[(k4 * 4 + j) * 64 + lane];
            float s0j = (&s0.x)[j], s1j = (&s1.x)[j];
            a00 += s0j * w.x; a01 += s0j * w.y;
            a10 += s1j * w.x; a11 += s1j * w.y;
        }
    }
    float bb0 = b2[lane], bb64 = b2[lane + 64];
    h2[(node0 + 0) * HID + lane]      = fmaxf(di[0] * a00 + bb0, 0.0f);
    h2[(node0 + 0) * HID + 64 + lane] = fmaxf(di[0] * a01 + bb64, 0.0f);
    h2[(node0 + 1) * HID + lane]      = fmaxf(di[1] * a10 + bb0, 0.0f);
    h2[(node0 + 1) * HID + 64 + lane] = fmaxf(di[1] * a11 + bb64, 0.0f);
}

// ---------------- heads: q = relu(h2@Wq + Bq) . wb + bb  (both heads, block GEMM)

__global__ __launch_bounds__(256) void k_heads(const float* __restrict__ x,
                                               const float* __restrict__ W1, const float* __restrict__ B1,
                                               const float* __restrict__ w1b, const float* __restrict__ b1b,
                                               const float* __restrict__ W2, const float* __restrict__ B2,
                                               const float* __restrict__ w2b, const float* __restrict__ b2b,
                                               float* __restrict__ q1, float* __restrict__ q2) {
    __shared__ float xs[16 * 128];
    __shared__ float w1s[32 * 128];
    __shared__ float w2s[32 * 128];
    __shared__ float part1[4][8];
    __shared__ float part2[4][8];
    int t = threadIdx.x;
    int row0 = blockIdx.x * 16;
    {
        float4* xsp = (float4*)xs;
        const float4* xp = (const float4*)(x + row0 * 128);
        for (int i = t; i < 512; i += 256) xsp[i] = xp[i];
    }
    int c = t & 127, half = t >> 7;
    float a1[8] = {0, 0, 0, 0, 0, 0, 0, 0};
    float a2[8] = {0, 0, 0, 0, 0, 0, 0, 0};
    for (int ch = 0; ch < 4; ++ch) {
        __syncthreads();
        {
            float4* w1p = (float4*)w1s;
            float4* w2p = (float4*)w2s;
            const float4* W1p = (const float4*)(W1 + ch * 4096);
            const float4* W2p = (const float4*)(W2 + ch * 4096);
            for (int i = t; i < 1024; i += 256) {
                w1p[i] = W1p[i];
                w2p[i] = W2p[i];
            }
        }
        __syncthreads();
        for (int k = 0; k < 32; ++k) {
            float wv1 = w1s[k * 128 + c];
            float wv2 = w2s[k * 128 + c];
#pragma unroll
            for (int r = 0; r < 8; ++r) {
                float xv = xs[(half * 8 + r) * 128 + ch * 32 + k];
                a1[r] += xv * wv1;
                a2[r] += xv * wv2;
            }
        }
    }
    float bb1 = B1[c], bb2 = B2[c];
    float v1 = w1b[c], v2 = w2b[c];
    float s1[8], s2[8];
#pragma unroll
    for (int r = 0; r < 8; ++r) {
        s1[r] = fmaxf(a1[r] + bb1, 0.0f) * v1;
        s2[r] = fmaxf(a2[r] + bb2, 0.0f) * v2;
    }
#pragma unroll
    for (int off = 1; off < 64; off <<= 1) {
#pragma unroll
        for (int r = 0; r < 8; ++r) {
            s1[r] += __shfl_xor(s1[r], off);
            s2[r] += __shfl_xor(s2[r], off);
        }
    }
    int wave = t >> 6, lane = t & 63;
    if (lane == 0) {
#pragma unroll
        for (int r = 0; r < 8; ++r) {
            part1[wave][r] = s1[r];
            part2[wave][r] = s2[r];
        }
    }
    __syncthreads();
    if (t < 16) {
        int hf = t >> 3, r = t & 7;
        int row = row0 + hf * 8 + r;
        q1[row] = part1[hf * 2][r] + part1[hf * 2 + 1][r] + b1b[0];
        q2[row] = part2[hf * 2][r] + part2[hf * 2 + 1][r] + b2b[0];
    }
}

extern "C" void kernel_launch(void* const* d_in, const int* in_sizes, int n_in,
                              void* d_out, int out_size, void* d_ws, size_t ws_size,
                              hipStream_t stream) {
    (void)in_sizes; (void)n_in; (void)out_size; (void)ws_size;
    const float* obs  = (const float*)d_in[0];
    const float* act  = (const float*)d_in[1];
    const int*   ei   = (const int*)d_in[2];
    const int*   src  = ei;
    const int*   dst  = ei + N_EDGES;
    const float* w_g1 = (const float*)d_in[3];
    const float* b_g1 = (const float*)d_in[4];
    const float* w_g2 = (const float*)d_in[5];
    const float* b_g2 = (const float*)d_in[6];
    const float* w_q1a = (const float*)d_in[7];
    const float* b_q1a = (const float*)d_in[8];
    const float* w_q1b = (const float*)d_in[9];
    const float* b_q1b = (const float*)d_in[10];
    const float* w_q2a = (const float*)d_in[11];
    const float* b_q2a = (const float*)d_in[12];
    const float* w_q2b = (const float*)d_in[13];
    const float* b_q2b = (const float*)d_in[14];
    float* out = (float*)d_out;

    char* ws = (char*)d_ws;
    size_t off = 0;
    auto alloc = [&](size_t bytes) {
        void* p = ws + off;
        off = (off + bytes + 255) & ~(size_t)255;
        return p;
    };
    int*   cnt  = (int*)alloc((N_NODES + 1) * 4);
    int*   col  = (int*)alloc((size_t)N_NODES * ELL_W * 4);
    float* xpad = (float*)alloc((size_t)(N_NODES + 1) * 64 * 4);
    float* ph1  = (float*)alloc((size_t)(N_NODES + 1) * HID * 4);  // +sentinel row
    float* h2b  = (float*)alloc((size_t)N_NODES * HID * 4);

    k_init<<<((N_NODES + 1) * 16 + 255) / 256, 256, 0, stream>>>(cnt, xpad, ph1, obs, act);
    k_build<<<(N_EDGES / 4 + 255) / 256, 256, 0, stream>>>(
        (const int4*)src, (const int4*)dst, cnt, col);
    k_l1<<<1250, 512, 0, stream>>>((const float4*)xpad, cnt, col, w_g1, b_g1, ph1);
    k_aggW2<<<625, 512, 0, stream>>>((const float4*)ph1, cnt, col, w_g2, b_g2, h2b);
    k_heads<<<625, 256, 0, stream>>>(h2b, w_q1a, b_q1a, w_q1b, b_q1b,
                                     w_q2a, b_q2a, w_q2b, b_q2b,
                                     out, out + N_NODES);
}

// Round 12
// 104.167 us; speedup vs baseline: 10.3830x; 1.1070x over previous
//
#include <hip/hip_runtime.h>

#define N_NODES 10000
#define N_EDGES 320000
#define OBS_DIM 30
#define ACT_DIM 4
#define HID 128
#define ELL_W 96   // padded neighbor-list width; deg ~Poisson(32), P(deg>88) ~ 1e-12
#define SENT N_NODES

// ---------------- init: cnt=0, xpad rows (obs|act|0)+zero sentinel, ph1 sentinel row=0

__global__ __launch_bounds__(256) void k_init(int* __restrict__ cnt,
                                              float* __restrict__ xpad,
                                              float* __restrict__ ph1,
                                              const float* __restrict__ obs,
                                              const float* __restrict__ act) {
    int i = blockIdx.x * 256 + threadIdx.x;
    if (i < (N_NODES + 1) * 16) {
        int row = i >> 4, sub = i & 15;
        float4 v = make_float4(0.f, 0.f, 0.f, 0.f);
        if (row < N_NODES) {
            float* vv = &v.x;
#pragma unroll
            for (int k = 0; k < 4; ++k) {
                int c = sub * 4 + k;
                if (c < OBS_DIM) vv[k] = obs[row * OBS_DIM + c];
                else if (c < OBS_DIM + ACT_DIM) vv[k] = act[row * ACT_DIM + (c - OBS_DIM)];
            }
        }
        ((float4*)xpad)[i] = v;
    }
    if (i <= N_NODES) cnt[i] = 0;
    if (i < HID / 4)
        ((float4*)(ph1 + (size_t)SENT * HID))[i] = make_float4(0.f, 0.f, 0.f, 0.f);
}

// ---------------- build: one atomic per edge reserves ELL slot AND counts degree ----------------

__global__ __launch_bounds__(256) void k_build(const int4* __restrict__ src4,
                                               const int4* __restrict__ dst4,
                                               int* __restrict__ cnt,
                                               int* __restrict__ col) {
    int i = blockIdx.x * 256 + threadIdx.x;
    if (i < N_EDGES / 4) {
        int4 s = src4[i];
        int4 d = dst4[i];
        int p;
        p = atomicAdd(&cnt[d.x], 1); col[d.x * ELL_W + p] = s.x;
        p = atomicAdd(&cnt[d.y], 1); col[d.y * ELL_W + p] = s.y;
        p = atomicAdd(&cnt[d.z], 1); col[d.z * ELL_W + p] = s.z;
        p = atomicAdd(&cnt[d.w], 1); col[d.w * ELL_W + p] = s.w;
    }
}

// ---------------- l1: z_i = d_i*(sum_j d_j x_j + d_i x_i)  (34-dim gather)
//                  ph1_i = d_i * relu(z_i @ W1 + b1)   [per-wave GEMV, W1 staged once]

__global__ __launch_bounds__(512) void k_l1(const float4* __restrict__ x4,
                                            const int* __restrict__ cnt,
                                            const int* __restrict__ col,
                                            const float* __restrict__ W1,
                                            const float* __restrict__ b1,
                                            float* __restrict__ ph1) {
    __shared__ float w1s[34 * 128];
    __shared__ float zs[8][64];
    int t = threadIdx.x;
    {
        float4* wsp = (float4*)w1s;
        const float4* Wp = (const float4*)W1;
        for (int i = t; i < 1088; i += 512) wsp[i] = Wp[i];
    }
    __syncthreads();
    int wave = t >> 6, lane = t & 63, g = lane >> 4, sub = lane & 15;
    int node = blockIdx.x * 8 + wave;  // 1250*8 = 10000 exactly
    int deg = cnt[node];
    float di = rsqrtf((float)(deg + 1));
    const int* cp = col + node * ELL_W;
    float4 a = make_float4(0.f, 0.f, 0.f, 0.f);
    if (g == 0) {
        float4 xv = x4[node * 16 + sub];
        a.x = di * xv.x; a.y = di * xv.y; a.z = di * xv.z; a.w = di * xv.w;
    }
    for (int e = 0; e < deg; e += 8) {
        int s0 = e + g, s1 = e + 4 + g;
        int j0 = (s0 < deg) ? cp[s0] : SENT;  // cnt[SENT]=0 -> d=1; x4[SENT]=0
        int j1 = (s1 < deg) ? cp[s1] : SENT;
        float d0 = rsqrtf((float)(cnt[j0] + 1));
        float d1 = rsqrtf((float)(cnt[j1] + 1));
        float4 v0 = x4[j0 * 16 + sub];
        float4 v1 = x4[j1 * 16 + sub];
        a.x += d0 * v0.x + d1 * v1.x;
        a.y += d0 * v0.y + d1 * v1.y;
        a.z += d0 * v0.z + d1 * v1.z;
        a.w += d0 * v0.w + d1 * v1.w;
    }
    a.x += __shfl_xor(a.x, 16); a.x += __shfl_xor(a.x, 32);
    a.y += __shfl_xor(a.y, 16); a.y += __shfl_xor(a.y, 32);
    a.z += __shfl_xor(a.z, 16); a.z += __shfl_xor(a.z, 32);
    a.w += __shfl_xor(a.w, 16); a.w += __shfl_xor(a.w, 32);
    if (g == 0) {
        float4 z;
        z.x = di * a.x; z.y = di * a.y; z.z = di * a.z; z.w = di * a.w;
        *(float4*)&zs[wave][sub * 4] = z;
    }
    // per-wave GEMV (zs same-wave write/read; compiler inserts lgkmcnt)
    float h0 = b1[lane], h64 = b1[lane + 64];
#pragma unroll
    for (int k = 0; k < 34; ++k) {
        float zk = zs[wave][k];
        h0 += zk * w1s[k * 128 + lane];
        h64 += zk * w1s[k * 128 + 64 + lane];
    }
    ph1[node * HID + lane] = di * fmaxf(h0, 0.0f);
    ph1[node * HID + 64 + lane] = di * fmaxf(h64, 0.0f);
}

// ---------------- agg2: s_i = sum_{j in N(i)} ph1_j + ph1_i   (pure gather, zero LDS)
// 2500 blocks x 4 waves, 1 node/wave; 16 slots/iter = 8 float4 loads in flight.

__global__ __launch_bounds__(256) void k_agg2(const float4* __restrict__ ph14,
                                              const int* __restrict__ cnt,
                                              const int* __restrict__ col,
                                              float4* __restrict__ sbuf) {
    int t = threadIdx.x;
    int wave = t >> 6, lane = t & 63, half = lane >> 5, sub = lane & 31;
    int node = blockIdx.x * 4 + wave;
    int deg = cnt[node];
    const int* cp = col + node * ELL_W;
    float4 a = make_float4(0.f, 0.f, 0.f, 0.f);
    float4 b = make_float4(0.f, 0.f, 0.f, 0.f);
    if (!half) a = ph14[node * 32 + sub];  // self term
    for (int e = 0; e < deg; e += 16) {
        int jj[8];
#pragma unroll
        for (int u = 0; u < 8; ++u) {
            int s = e + 2 * u + half;
            jj[u] = (s < deg) ? cp[s] : SENT;  // ph1[SENT] row = 0
        }
        float4 v0 = ph14[jj[0] * 32 + sub];
        float4 v1 = ph14[jj[1] * 32 + sub];
        float4 v2 = ph14[jj[2] * 32 + sub];
        float4 v3 = ph14[jj[3] * 32 + sub];
        float4 v4 = ph14[jj[4] * 32 + sub];
        float4 v5 = ph14[jj[5] * 32 + sub];
        float4 v6 = ph14[jj[6] * 32 + sub];
        float4 v7 = ph14[jj[7] * 32 + sub];
        a.x += (v0.x + v1.x) + (v2.x + v3.x);
        a.y += (v0.y + v1.y) + (v2.y + v3.y);
        a.z += (v0.z + v1.z) + (v2.z + v3.z);
        a.w += (v0.w + v1.w) + (v2.w + v3.w);
        b.x += (v4.x + v5.x) + (v6.x + v7.x);
        b.y += (v4.y + v5.y) + (v6.y + v7.y);
        b.z += (v4.z + v5.z) + (v6.z + v7.z);
        b.w += (v4.w + v5.w) + (v6.w + v7.w);
    }
    a.x += b.x; a.y += b.y; a.z += b.z; a.w += b.w;
    a.x += __shfl_xor(a.x, 32);
    a.y += __shfl_xor(a.y, 32);
    a.z += __shfl_xor(a.z, 32);
    a.w += __shfl_xor(a.w, 32);
    if (!half) sbuf[node * 32 + sub] = a;
}

// ---------------- h2heads: h2 = relu(d_i*(s@W2)+b2); q = relu(h2@Wq+Bq).wb + bb
// 625 blocks x 16 rows; pure LDS-staged GEMM chain (no gather -> no occupancy conflict).

__global__ __launch_bounds__(256) void k_h2heads(const float4* __restrict__ sbuf4,
                                                 const int* __restrict__ cnt,
                                                 const float* __restrict__ W2, const float* __restrict__ b2,
                                                 const float* __restrict__ Wq1, const float* __restrict__ Bq1,
                                                 const float* __restrict__ w1b, const float* __restrict__ b1b,
                                                 const float* __restrict__ Wq2, const float* __restrict__ Bq2,
                                                 const float* __restrict__ w2b, const float* __restrict__ b2b,
                                                 float* __restrict__ q1, float* __restrict__ q2) {
    __shared__ float xs[16 * 128];    // s tile (8 KB)
    __shared__ float hs[16 * 128];    // h2 tile (8 KB)
    __shared__ float wbA[32 * 128];   // chunk buf (16 KB)
    __shared__ float wbB[32 * 128];   // chunk buf (16 KB)
    __shared__ float part1[4][8], part2[4][8];
    int t = threadIdx.x;
    int row0 = blockIdx.x * 16;
    {
        float4* xsp = (float4*)xs;
        for (int i = t; i < 512; i += 256) xsp[i] = sbuf4[row0 * 32 + i];
    }
    int c = t & 127, q = t >> 7;
    // ---- y2 = s @ W2 (4 chunks)
    float acc[8] = {0, 0, 0, 0, 0, 0, 0, 0};
    for (int ch = 0; ch < 4; ++ch) {
        __syncthreads();  // first iter: xs ready; later: wbA reads done
        {
            float4* wp = (float4*)wbA;
            const float4* Wp = (const float4*)(W2 + ch * 4096);
            for (int i = t; i < 1024; i += 256) wp[i] = Wp[i];
        }
        __syncthreads();
        for (int k = 0; k < 32; ++k) {
            float wv = wbA[k * 128 + c];
#pragma unroll
            for (int r = 0; r < 8; ++r)
                acc[r] += xs[(q * 8 + r) * 128 + ch * 32 + k] * wv;
        }
    }
    // h2 = relu(d_row * y2 + b2) -> hs
    {
        float bb = b2[c];
#pragma unroll
        for (int r = 0; r < 8; ++r) {
            int row = row0 + q * 8 + r;
            float dr = rsqrtf((float)(cnt[row] + 1));
            hs[(q * 8 + r) * 128 + c] = fmaxf(dr * acc[r] + bb, 0.0f);
        }
    }
    // ---- heads on hs (4 chunks, both heads)
    float a1[8] = {0, 0, 0, 0, 0, 0, 0, 0};
    float a2[8] = {0, 0, 0, 0, 0, 0, 0, 0};
    for (int ch = 0; ch < 4; ++ch) {
        __syncthreads();  // first iter: hs complete; later: wb reads done
        {
            float4* w1p = (float4*)wbA;
            float4* w2p = (float4*)wbB;
            const float4* W1p = (const float4*)(Wq1 + ch * 4096);
            const float4* W2p = (const float4*)(Wq2 + ch * 4096);
            for (int i = t; i < 1024; i += 256) {
                w1p[i] = W1p[i];
                w2p[i] = W2p[i];
            }
        }
        __syncthreads();
        for (int k = 0; k < 32; ++k) {
            float wv1 = wbA[k * 128 + c];
            float wv2 = wbB[k * 128 + c];
#pragma unroll
            for (int r = 0; r < 8; ++r) {
                float xv = hs[(q * 8 + r) * 128 + ch * 32 + k];
                a1[r] += xv * wv1;
                a2[r] += xv * wv2;
            }
        }
    }
    float bb1 = Bq1[c], bb2 = Bq2[c];
    float v1 = w1b[c], v2 = w2b[c];
    float s1[8], s2[8];
#pragma unroll
    for (int r = 0; r < 8; ++r) {
        s1[r] = fmaxf(a1[r] + bb1, 0.0f) * v1;
        s2[r] = fmaxf(a2[r] + bb2, 0.0f) * v2;
    }
#pragma unroll
    for (int off = 1; off < 64; off <<= 1) {
#pragma unroll
        for (int r = 0; r < 8; ++r) {
            s1[r] += __shfl_xor(s1[r], off);
            s2[r] += __shfl_xor(s2[r], off);
        }
    }
    int wave = t >> 6, lane = t & 63;
    if (lane == 0) {
#pragma unroll
        for (int r = 0; r < 8; ++r) {
            part1[wave][r] = s1[r];
            part2[wave][r] = s2[r];
        }
    }
    __syncthreads();
    if (t < 16) {
        int hf = t >> 3, r = t & 7;
        int row = row0 + hf * 8 + r;
        q1[row] = part1[hf * 2][r] + part1[hf * 2 + 1][r] + b1b[0];
        q2[row] = part2[hf * 2][r] + part2[hf * 2 + 1][r] + b2b[0];
    }
}

extern "C" void kernel_launch(void* const* d_in, const int* in_sizes, int n_in,
                              void* d_out, int out_size, void* d_ws, size_t ws_size,
                              hipStream_t stream) {
    (void)in_sizes; (void)n_in; (void)out_size; (void)ws_size;
    const float* obs  = (const float*)d_in[0];
    const float* act  = (const float*)d_in[1];
    const int*   ei   = (const int*)d_in[2];
    const int*   src  = ei;
    const int*   dst  = ei + N_EDGES;
    const float* w_g1 = (const float*)d_in[3];
    const float* b_g1 = (const float*)d_in[4];
    const float* w_g2 = (const float*)d_in[5];
    const float* b_g2 = (const float*)d_in[6];
    const float* w_q1a = (const float*)d_in[7];
    const float* b_q1a = (const float*)d_in[8];
    const float* w_q1b = (const float*)d_in[9];
    const float* b_q1b = (const float*)d_in[10];
    const float* w_q2a = (const float*)d_in[11];
    const float* b_q2a = (const float*)d_in[12];
    const float* w_q2b = (const float*)d_in[13];
    const float* b_q2b = (const float*)d_in[14];
    float* out = (float*)d_out;

    char* ws = (char*)d_ws;
    size_t off = 0;
    auto alloc = [&](size_t bytes) {
        void* p = ws + off;
        off = (off + bytes + 255) & ~(size_t)255;
        return p;
    };
    int*   cnt  = (int*)alloc((N_NODES + 1) * 4);
    int*   col  = (int*)alloc((size_t)N_NODES * ELL_W * 4);
    float* xpad = (float*)alloc((size_t)(N_NODES + 1) * 64 * 4);
    float* ph1  = (float*)alloc((size_t)(N_NODES + 1) * HID * 4);  // +sentinel row
    float* sbuf = (float*)alloc((size_t)N_NODES * HID * 4);

    k_init<<<((N_NODES + 1) * 16 + 255) / 256, 256, 0, stream>>>(cnt, xpad, ph1, obs, act);
    k_build<<<(N_EDGES / 4 + 255) / 256, 256, 0, stream>>>(
        (const int4*)src, (const int4*)dst, cnt, col);
    k_l1<<<1250, 512, 0, stream>>>((const float4*)xpad, cnt, col, w_g1, b_g1, ph1);
    k_agg2<<<2500, 256, 0, stream>>>((const float4*)ph1, cnt, col, (float4*)sbuf);
    k_h2heads<<<625, 256, 0, stream>>>((const float4*)sbuf, cnt,
                                       w_g2, b_g2,
                                       w_q1a, b_q1a, w_q1b, b_q1b,
                                       w_q2a, b_q2a, w_q2b, b_q2b,
                                       out, out + N_NODES);
}

// Round 13
// 93.742 us; speedup vs baseline: 11.5377x; 1.1112x over previous
//
#include <hip/hip_runtime.h>

#define N_NODES 10000
#define N_EDGES 320000
#define OBS_DIM 30
#define ACT_DIM 4
#define HID 128
#define ELL_W 96   // padded neighbor-list width; deg ~Poisson(32), P(deg>88) ~ 1e-12
#define SENT N_NODES

// ---------------- init: cnt=0, xpad rows (obs|act|0)+zero sentinel, ph1 sentinel row=0

__global__ __launch_bounds__(256) void k_init(int* __restrict__ cnt,
                                              float* __restrict__ xpad,
                                              float* __restrict__ ph1,
                                              const float* __restrict__ obs,
                                              const float* __restrict__ act) {
    int i = blockIdx.x * 256 + threadIdx.x;
    if (i < (N_NODES + 1) * 16) {
        int row = i >> 4, sub = i & 15;
        float4 v = make_float4(0.f, 0.f, 0.f, 0.f);
        if (row < N_NODES) {
            float* vv = &v.x;
#pragma unroll
            for (int k = 0; k < 4; ++k) {
                int c = sub * 4 + k;
                if (c < OBS_DIM) vv[k] = obs[row * OBS_DIM + c];
                else if (c < OBS_DIM + ACT_DIM) vv[k] = act[row * ACT_DIM + (c - OBS_DIM)];
            }
        }
        ((float4*)xpad)[i] = v;
    }
    if (i <= N_NODES) cnt[i] = 0;
    if (i < HID / 4)
        ((float4*)(ph1 + (size_t)SENT * HID))[i] = make_float4(0.f, 0.f, 0.f, 0.f);
}

// ---------------- build: one atomic per edge reserves ELL slot AND counts degree ----------------

__global__ __launch_bounds__(256) void k_build(const int4* __restrict__ src4,
                                               const int4* __restrict__ dst4,
                                               int* __restrict__ cnt,
                                               int* __restrict__ col) {
    int i = blockIdx.x * 256 + threadIdx.x;
    if (i < N_EDGES / 4) {
        int4 s = src4[i];
        int4 d = dst4[i];
        int p;
        p = atomicAdd(&cnt[d.x], 1); col[d.x * ELL_W + p] = s.x;
        p = atomicAdd(&cnt[d.y], 1); col[d.y * ELL_W + p] = s.y;
        p = atomicAdd(&cnt[d.z], 1); col[d.z * ELL_W + p] = s.z;
        p = atomicAdd(&cnt[d.w], 1); col[d.w * ELL_W + p] = s.w;
    }
}

// ---------------- l1: z_i = d_i*(sum_j d_j x_j + d_i x_i)  (34-dim gather)
//                  ph1_i = d_i * relu(z_i @ W1 + b1)   [per-wave GEMV, W1 staged once]

__global__ __launch_bounds__(512) void k_l1(const float4* __restrict__ x4,
                                            const int* __restrict__ cnt,
                                            const int* __restrict__ col,
                                            const float* __restrict__ W1,
                                            const float* __restrict__ b1,
                                            float* __restrict__ ph1) {
    __shared__ float w1s[34 * 128];
    __shared__ float zs[8][64];
    int t = threadIdx.x;
    {
        float4* wsp = (float4*)w1s;
        const float4* Wp = (const float4*)W1;
        for (int i = t; i < 1088; i += 512) wsp[i] = Wp[i];
    }
    __syncthreads();
    int wave = t >> 6, lane = t & 63, g = lane >> 4, sub = lane & 15;
    int node = blockIdx.x * 8 + wave;  // 1250*8 = 10000 exactly
    int deg = cnt[node];
    float di = rsqrtf((float)(deg + 1));
    const int* cp = col + node * ELL_W;
    float4 a = make_float4(0.f, 0.f, 0.f, 0.f);
    if (g == 0) {
        float4 xv = x4[node * 16 + sub];
        a.x = di * xv.x; a.y = di * xv.y; a.z = di * xv.z; a.w = di * xv.w;
    }
    for (int e = 0; e < deg; e += 8) {
        int s0 = e + g, s1 = e + 4 + g;
        int j0 = (s0 < deg) ? cp[s0] : SENT;  // cnt[SENT]=0 -> d=1; x4[SENT]=0
        int j1 = (s1 < deg) ? cp[s1] : SENT;
        float d0 = rsqrtf((float)(cnt[j0] + 1));
        float d1 = rsqrtf((float)(cnt[j1] + 1));
        float4 v0 = x4[j0 * 16 + sub];
        float4 v1 = x4[j1 * 16 + sub];
        a.x += d0 * v0.x + d1 * v1.x;
        a.y += d0 * v0.y + d1 * v1.y;
        a.z += d0 * v0.z + d1 * v1.z;
        a.w += d0 * v0.w + d1 * v1.w;
    }
    a.x += __shfl_xor(a.x, 16); a.x += __shfl_xor(a.x, 32);
    a.y += __shfl_xor(a.y, 16); a.y += __shfl_xor(a.y, 32);
    a.z += __shfl_xor(a.z, 16); a.z += __shfl_xor(a.z, 32);
    a.w += __shfl_xor(a.w, 16); a.w += __shfl_xor(a.w, 32);
    if (g == 0) {
        float4 z;
        z.x = di * a.x; z.y = di * a.y; z.z = di * a.z; z.w = di * a.w;
        *(float4*)&zs[wave][sub * 4] = z;
    }
    // per-wave GEMV (zs same-wave write/read; compiler inserts lgkmcnt)
    float h0 = b1[lane], h64 = b1[lane + 64];
#pragma unroll
    for (int k = 0; k < 34; ++k) {
        float zk = zs[wave][k];
        h0 += zk * w1s[k * 128 + lane];
        h64 += zk * w1s[k * 128 + 64 + lane];
    }
    ph1[node * HID + lane] = di * fmaxf(h0, 0.0f);
    ph1[node * HID + 64 + lane] = di * fmaxf(h64, 0.0f);
}

// ---------------- agg2: s_i = sum_{j in N(i)} ph1_j + ph1_i   (pure gather, zero LDS)

__global__ __launch_bounds__(256) void k_agg2(const float4* __restrict__ ph14,
                                              const int* __restrict__ cnt,
                                              const int* __restrict__ col,
                                              float4* __restrict__ sbuf) {
    int t = threadIdx.x;
    int wave = t >> 6, lane = t & 63, half = lane >> 5, sub = lane & 31;
    int node = blockIdx.x * 4 + wave;
    int deg = cnt[node];
    const int* cp = col + node * ELL_W;
    float4 a = make_float4(0.f, 0.f, 0.f, 0.f);
    float4 b = make_float4(0.f, 0.f, 0.f, 0.f);
    if (!half) a = ph14[node * 32 + sub];  // self term
    for (int e = 0; e < deg; e += 16) {
        int jj[8];
#pragma unroll
        for (int u = 0; u < 8; ++u) {
            int s = e + 2 * u + half;
            jj[u] = (s < deg) ? cp[s] : SENT;  // ph1[SENT] row = 0
        }
        float4 v0 = ph14[jj[0] * 32 + sub];
        float4 v1 = ph14[jj[1] * 32 + sub];
        float4 v2 = ph14[jj[2] * 32 + sub];
        float4 v3 = ph14[jj[3] * 32 + sub];
        float4 v4 = ph14[jj[4] * 32 + sub];
        float4 v5 = ph14[jj[5] * 32 + sub];
        float4 v6 = ph14[jj[6] * 32 + sub];
        float4 v7 = ph14[jj[7] * 32 + sub];
        a.x += (v0.x + v1.x) + (v2.x + v3.x);
        a.y += (v0.y + v1.y) + (v2.y + v3.y);
        a.z += (v0.z + v1.z) + (v2.z + v3.z);
        a.w += (v0.w + v1.w) + (v2.w + v3.w);
        b.x += (v4.x + v5.x) + (v6.x + v7.x);
        b.y += (v4.y + v5.y) + (v6.y + v7.y);
        b.z += (v4.z + v5.z) + (v6.z + v7.z);
        b.w += (v4.w + v5.w) + (v6.w + v7.w);
    }
    a.x += b.x; a.y += b.y; a.z += b.z; a.w += b.w;
    a.x += __shfl_xor(a.x, 32);
    a.y += __shfl_xor(a.y, 32);
    a.z += __shfl_xor(a.z, 32);
    a.w += __shfl_xor(a.w, 32);
    if (!half) sbuf[node * 32 + sub] = a;
}

// ---------------- h2heads: h2 = relu(d_i*(s@W2)+b2); q = relu(h2@Wq+Bq).wb + bb
// 625 blocks x 16 rows. Thread tile = 4 rows x 2 cols; wave owns 4 full rows ->
// xs reads are wave-uniform b128 broadcasts; head reduce is pure 64-lane shuffle.

__global__ __launch_bounds__(256) void k_h2heads(const float4* __restrict__ sbuf4,
                                                 const int* __restrict__ cnt,
                                                 const float* __restrict__ W2, const float* __restrict__ b2,
                                                 const float* __restrict__ Wq1, const float* __restrict__ Bq1,
                                                 const float* __restrict__ w1b, const float* __restrict__ b1b,
                                                 const float* __restrict__ Wq2, const float* __restrict__ Bq2,
                                                 const float* __restrict__ w2b, const float* __restrict__ b2b,
                                                 float* __restrict__ q1, float* __restrict__ q2) {
    __shared__ float xs[16 * 128];    // s tile (8 KB)
    __shared__ float hs[16 * 128];    // h2 tile (8 KB)
    __shared__ float wbA[32 * 128];   // chunk buf (16 KB)
    __shared__ float wbB[32 * 128];   // chunk buf (16 KB)
    int t = threadIdx.x;
    int row0 = blockIdx.x * 16;
    {
        float4* xsp = (float4*)xs;
        for (int i = t; i < 512; i += 256) xsp[i] = sbuf4[row0 * 32 + i];
    }
    int cp = t & 63, rg = t >> 6;  // wave rg owns rows rg*4..rg*4+3; cols cp, cp+64
    // ---- y2 = s @ W2 (4 chunks of 32 k)
    float acc[4][2] = {{0, 0}, {0, 0}, {0, 0}, {0, 0}};
    for (int ch = 0; ch < 4; ++ch) {
        __syncthreads();  // first iter: xs ready; later: wbA reads done
        {
            float4* wp = (float4*)wbA;
            const float4* Wp = (const float4*)(W2 + ch * 4096);
            for (int i = t; i < 1024; i += 256) wp[i] = Wp[i];
        }
        __syncthreads();
        for (int k4 = 0; k4 < 8; ++k4) {
            float4 x0 = *(const float4*)&xs[(rg * 4 + 0) * 128 + ch * 32 + k4 * 4];
            float4 x1 = *(const float4*)&xs[(rg * 4 + 1) * 128 + ch * 32 + k4 * 4];
            float4 x2 = *(const float4*)&xs[(rg * 4 + 2) * 128 + ch * 32 + k4 * 4];
            float4 x3 = *(const float4*)&xs[(rg * 4 + 3) * 128 + ch * 32 + k4 * 4];
#pragma unroll
            for (int j = 0; j < 4; ++j) {
                int k = k4 * 4 + j;
                float w0 = wbA[k * 128 + cp];
                float w1 = wbA[k * 128 + cp + 64];
                acc[0][0] += (&x0.x)[j] * w0; acc[0][1] += (&x0.x)[j] * w1;
                acc[1][0] += (&x1.x)[j] * w0; acc[1][1] += (&x1.x)[j] * w1;
                acc[2][0] += (&x2.x)[j] * w0; acc[2][1] += (&x2.x)[j] * w1;
                acc[3][0] += (&x3.x)[j] * w0; acc[3][1] += (&x3.x)[j] * w1;
            }
        }
    }
    // h2 = relu(d_row * y2 + b2) -> hs
    {
        float bb0 = b2[cp], bb64 = b2[cp + 64];
#pragma unroll
        for (int r = 0; r < 4; ++r) {
            int row = row0 + rg * 4 + r;
            float dr = rsqrtf((float)(cnt[row] + 1));
            hs[(rg * 4 + r) * 128 + cp] = fmaxf(dr * acc[r][0] + bb0, 0.0f);
            hs[(rg * 4 + r) * 128 + cp + 64] = fmaxf(dr * acc[r][1] + bb64, 0.0f);
        }
    }
    // ---- both heads on hs (4 chunks)
    float a1[4][2] = {{0, 0}, {0, 0}, {0, 0}, {0, 0}};
    float a2[4][2] = {{0, 0}, {0, 0}, {0, 0}, {0, 0}};
    for (int ch = 0; ch < 4; ++ch) {
        __syncthreads();  // first iter: hs complete; later: wb reads done
        {
            float4* w1p = (float4*)wbA;
            float4* w2p = (float4*)wbB;
            const float4* W1p = (const float4*)(Wq1 + ch * 4096);
            const float4* W2p = (const float4*)(Wq2 + ch * 4096);
            for (int i = t; i < 1024; i += 256) {
                w1p[i] = W1p[i];
                w2p[i] = W2p[i];
            }
        }
        __syncthreads();
        for (int k4 = 0; k4 < 8; ++k4) {
            float4 x0 = *(const float4*)&hs[(rg * 4 + 0) * 128 + ch * 32 + k4 * 4];
            float4 x1 = *(const float4*)&hs[(rg * 4 + 1) * 128 + ch * 32 + k4 * 4];
            float4 x2 = *(const float4*)&hs[(rg * 4 + 2) * 128 + ch * 32 + k4 * 4];
            float4 x3 = *(const float4*)&hs[(rg * 4 + 3) * 128 + ch * 32 + k4 * 4];
#pragma unroll
            for (int j = 0; j < 4; ++j) {
                int k = k4 * 4 + j;
                float wA0 = wbA[k * 128 + cp];
                float wA1 = wbA[k * 128 + cp + 64];
                float wB0 = wbB[k * 128 + cp];
                float wB1 = wbB[k * 128 + cp + 64];
                a1[0][0] += (&x0.x)[j] * wA0; a1[0][1] += (&x0.x)[j] * wA1;
                a1[1][0] += (&x1.x)[j] * wA0; a1[1][1] += (&x1.x)[j] * wA1;
                a1[2][0] += (&x2.x)[j] * wA0; a1[2][1] += (&x2.x)[j] * wA1;
                a1[3][0] += (&x3.x)[j] * wA0; a1[3][1] += (&x3.x)[j] * wA1;
                a2[0][0] += (&x0.x)[j] * wB0; a2[0][1] += (&x0.x)[j] * wB1;
                a2[1][0] += (&x1.x)[j] * wB0; a2[1][1] += (&x1.x)[j] * wB1;
                a2[2][0] += (&x2.x)[j] * wB0; a2[2][1] += (&x2.x)[j] * wB1;
                a2[3][0] += (&x3.x)[j] * wB0; a2[3][1] += (&x3.x)[j] * wB1;
            }
        }
    }
    // epilogue: per row, s = relu(a+B).wb summed over this lane's 2 cols; 64-lane reduce
    float B10 = Bq1[cp], B11 = Bq1[cp + 64];
    float B20 = Bq2[cp], B21 = Bq2[cp + 64];
    float v10 = w1b[cp], v11 = w1b[cp + 64];
    float v20 = w2b[cp], v21 = w2b[cp + 64];
    float s1[4], s2[4];
#pragma unroll
    for (int r = 0; r < 4; ++r) {
        s1[r] = fmaxf(a1[r][0] + B10, 0.0f) * v10 + fmaxf(a1[r][1] + B11, 0.0f) * v11;
        s2[r] = fmaxf(a2[r][0] + B20, 0.0f) * v20 + fmaxf(a2[r][1] + B21, 0.0f) * v21;
    }
#pragma unroll
    for (int off = 1; off < 64; off <<= 1) {
#pragma unroll
        for (int r = 0; r < 4; ++r) {
            s1[r] += __shfl_xor(s1[r], off);
            s2[r] += __shfl_xor(s2[r], off);
        }
    }
    if (cp == 0) {
#pragma unroll
        for (int r = 0; r < 4; ++r) {
            int row = row0 + rg * 4 + r;
            q1[row] = s1[r] + b1b[0];
            q2[row] = s2[r] + b2b[0];
        }
    }
}

extern "C" void kernel_launch(void* const* d_in, const int* in_sizes, int n_in,
                              void* d_out, int out_size, void* d_ws, size_t ws_size,
                              hipStream_t stream) {
    (void)in_sizes; (void)n_in; (void)out_size; (void)ws_size;
    const float* obs  = (const float*)d_in[0];
    const float* act  = (const float*)d_in[1];
    const int*   ei   = (const int*)d_in[2];
    const int*   src  = ei;
    const int*   dst  = ei + N_EDGES;
    const float* w_g1 = (const float*)d_in[3];
    const float* b_g1 = (const float*)d_in[4];
    const float* w_g2 = (const float*)d_in[5];
    const float* b_g2 = (const float*)d_in[6];
    const float* w_q1a = (const float*)d_in[7];
    const float* b_q1a = (const float*)d_in[8];
    const float* w_q1b = (const float*)d_in[9];
    const float* b_q1b = (const float*)d_in[10];
    const float* w_q2a = (const float*)d_in[11];
    const float* b_q2a = (const float*)d_in[12];
    const float* w_q2b = (const float*)d_in[13];
    const float* b_q2b = (const float*)d_in[14];
    float* out = (float*)d_out;

    char* ws = (char*)d_ws;
    size_t off = 0;
    auto alloc = [&](size_t bytes) {
        void* p = ws + off;
        off = (off + bytes + 255) & ~(size_t)255;
        return p;
    };
    int*   cnt  = (int*)alloc((N_NODES + 1) * 4);
    int*   col  = (int*)alloc((size_t)N_NODES * ELL_W * 4);
    float* xpad = (float*)alloc((size_t)(N_NODES + 1) * 64 * 4);
    float* ph1  = (float*)alloc((size_t)(N_NODES + 1) * HID * 4);  // +sentinel row
    float* sbuf = (float*)alloc((size_t)N_NODES * HID * 4);

    k_init<<<((N_NODES + 1) * 16 + 255) / 256, 256, 0, stream>>>(cnt, xpad, ph1, obs, act);
    k_build<<<(N_EDGES / 4 + 255) / 256, 256, 0, stream>>>(
        (const int4*)src, (const int4*)dst, cnt, col);
    k_l1<<<1250, 512, 0, stream>>>((const float4*)xpad, cnt, col, w_g1, b_g1, ph1);
    k_agg2<<<2500, 256, 0, stream>>>((const float4*)ph1, cnt, col, (float4*)sbuf);
    k_h2heads<<<625, 256, 0, stream>>>((const float4*)sbuf, cnt,
                                       w_g2, b_g2,
                                       w_q1a, b_q1a, w_q1b, b_q1b,
                                       w_q2a, b_q2a, w_q2b, b_q2b,
                                       out, out + N_NODES);
}